// Round 3
// baseline (328.618 us; speedup 1.0000x reference)
//
#include <hip/hip_runtime.h>

// Sparse submanifold 3D conv, f32, v_pk_fma_f32 edition.
// out[n,co] = bias[co] + sum_k sum_ci feats[nbr[n,k],ci] * W[k,ci,co]
// One wave per 32 output rows; lane = co (C_OUT==64).
// Each row body: 16 x v_pk_fma_f32 (packed ci,ci+1) -> halves FMA issue count
// vs scalar fmaf (issue floor ~146us -> ~73us). float2 partial sums combined
// at store. ~87% of (n,k) pairs are sentinel -> skipped via uniform branches.

typedef float v2f __attribute__((ext_vector_type(2)));
typedef float v4f __attribute__((ext_vector_type(4)));

// packed fma: acc = a*b + acc (2 lanes of f32 per instruction)
#define PK_FMA(acc, a, b) \
    asm("v_pk_fma_f32 %0, %1, %2, %0" : "+v"(acc) : "v"(a), "v"(b))

constexpr int C_IN_  = 32;
constexpr int C_OUT_ = 64;
constexpr int KVOL_  = 27;
constexpr int RPW    = 32;   // rows per wave
constexpr int WPB    = 4;    // waves per block

__global__ __launch_bounds__(256, 4)
void spconv_f32_kernel(const float* __restrict__ features,
                       const float* __restrict__ weight,
                       const float* __restrict__ bias,
                       const int*   __restrict__ nbr,
                       float*       __restrict__ out,
                       int n)
{
    const int lane = threadIdx.x & 63;          // 0..63 == output channel
    const int wid  = threadIdx.x >> 6;          // wave id in block
    const int wave = blockIdx.x * WPB + wid;    // global wave id
    const int r0   = wave * RPW;                // first output row
    if (r0 >= n) return;                        // wave-uniform

    // acc2[r] = packed partial sums (even ci, odd ci) for out[r0+r, lane]
    v2f acc2[RPW];
    const float b = bias[lane];
#pragma unroll
    for (int r = 0; r < RPW; ++r) acc2[r] = (v2f){b, 0.0f};

    const int  myrow = r0 + lane;                    // row probed by this lane
    const bool rowok = (lane < RPW) && (myrow < n);  // lanes 32..63 idle here

#pragma unroll 1
    for (int k = 0; k < KVOL_; ++k) {
        // Register-cache W[k][2j][lane], W[k][2j+1][lane] as packed pairs.
        // 32 coalesced 256B loads per k, amortized over 32 rows.
        v2f w2[C_IN_ / 2];
        const float* wk = weight + (size_t)k * (C_IN_ * C_OUT_) + lane;
#pragma unroll
        for (int j = 0; j < C_IN_ / 2; ++j) {
            v2f t;
            t.x = wk[(size_t)(2 * j)     * C_OUT_];
            t.y = wk[(size_t)(2 * j + 1) * C_OUT_];
            w2[j] = t;
        }

        // lane r (r<32) fetches the neighbor index for row r0+r at offset k
        int idxv = rowok ? nbr[(size_t)myrow * KVOL_ + k] : n;
        const unsigned long long mask = __ballot(idxv != n);  // bits 0..31

        // Fully unrolled: constant bit-test -> uniform scalar branch; acc2[]
        // statically indexed (no scratch).
#pragma unroll
        for (int r = 0; r < RPW; ++r) {
            if (mask & (1ull << r)) {
                const int idx = __builtin_amdgcn_readlane(idxv, r); // uniform
                const v4f* frow = (const v4f*)(features + (size_t)idx * C_IN_);
#pragma unroll
                for (int j = 0; j < C_IN_ / 4; ++j) {       // 8 x float4
                    v4f f  = frow[j];
                    v2f lo = __builtin_shufflevector(f, f, 0, 1);
                    v2f hi = __builtin_shufflevector(f, f, 2, 3);
                    PK_FMA(acc2[r], lo, w2[2 * j]);
                    PK_FMA(acc2[r], hi, w2[2 * j + 1]);
                }
            }
        }
    }

    // Coalesced store: 256B per row; combine packed partials
#pragma unroll
    for (int r = 0; r < RPW; ++r) {
        if (r0 + r < n)
            out[(size_t)(r0 + r) * C_OUT_ + lane] = acc2[r].x + acc2[r].y;
    }
}

extern "C" void kernel_launch(void* const* d_in, const int* in_sizes, int n_in,
                              void* d_out, int out_size, void* d_ws, size_t ws_size,
                              hipStream_t stream)
{
    const float* features = (const float*)d_in[0];   // (N, 32) f32
    const float* weight   = (const float*)d_in[1];   // (27, 32, 64) f32
    const float* bias     = (const float*)d_in[2];   // (64,) f32
    const int*   nbr      = (const int*)  d_in[3];   // (N, 27) i32, sentinel = N

    float* out = (float*)d_out;                      // (N, 64) f32

    const int n     = in_sizes[0] / C_IN_;
    const int waves = (n + RPW - 1) / RPW;
    const int grid  = (waves + WPB - 1) / WPB;

    spconv_f32_kernel<<<dim3(grid), dim3(256), 0, stream>>>(
        features, weight, bias, nbr, out, n);
}

// Round 4
// 150.222 us; speedup vs baseline: 2.1875x; 2.1875x over previous
//
#include <hip/hip_runtime.h>

// Sparse submanifold 3D conv via dense bf16 MFMA (32x32x16).
// out[n,co] = bias[co] + sum_k sum_ci feats[nbr[n,k],ci] * W[k,ci,co]
// Wave = 64 rows (2 tiles of 32) x 64 co. Per k: A = gathered feature rows
// (f32->bf16, sentinel lanes clamped to row 0 then zeroed), B = W[k] bf16
// fragments read from LDS (staged fragment-ordered once per block, 108 KiB).
// nbr indices for the wave's rows preloaded to registers; k-loop fully
// unrolled so all arrays stay statically indexed (no scratch).

typedef short  bf16x8 __attribute__((ext_vector_type(8)));
typedef float  f32x16 __attribute__((ext_vector_type(16)));
typedef float  f32x4a __attribute__((ext_vector_type(4)));
typedef int    i32x4u __attribute__((ext_vector_type(4), aligned(4)));
typedef int    i32x2u __attribute__((ext_vector_type(2), aligned(4)));

constexpr int CIN    = 32;
constexpr int COUT   = 64;
constexpr int KV     = 27;
constexpr int WAVES  = 8;
constexpr int RPWAVE = 64;                 // rows per wave (2 tiles of 32)
constexpr int RPB    = WAVES * RPWAVE;     // 512 rows per block

__device__ inline bf16x8 cvt8(f32x4a lo, f32x4a hi) {
    bf16x8 r;
#pragma unroll
    for (int j = 0; j < 4; ++j) {
        r[j]     = __builtin_bit_cast(short, (__bf16)lo[j]);
        r[4 + j] = __builtin_bit_cast(short, (__bf16)hi[j]);
    }
    return r;
}

// static-index accessor into the preloaded nbr registers (folds after unroll)
#define NIDX(A, B, C, k) ((k) < 24 ? (A)[(k) >> 2][(k) & 3] \
                                   : ((k) < 26 ? (B)[(k) - 24] : (C)))

__global__ __launch_bounds__(512, 2)
void spconv_mfma_kernel(const float* __restrict__ feats,
                        const float* __restrict__ weight,
                        const float* __restrict__ bias,
                        const int*   __restrict__ nbr,
                        float*       __restrict__ out,
                        int n)
{
    // B fragments: frag_id = k*4 + c*2 + h  (c = ci>>4 k-chunk, h = co>>5)
    // lane holds 8 bf16 at halfword off frag_id*512 + lane*8:
    //   element (kk, col): col = lane&31, kk = 8*(lane>>5) + j
    __shared__ __align__(16) unsigned short wlds[KV * 4 * 512];  // 108 KiB

    const int tid = threadIdx.x;
    const int lane = tid & 63;
    const int wv   = tid >> 6;
    const int l31  = lane & 31;
    const int e5   = lane >> 5;

    // ---- prologue: W (f32, [k][ci][co]) -> LDS bf16 fragment-ordered ----
    for (int i0 = tid * 4; i0 < KV * 2048; i0 += 2048) {
        const f32x4a w4 = *(const f32x4a*)(weight + i0);
#pragma unroll
        for (int m = 0; m < 4; ++m) {
            const int e    = i0 + m;
            const int k    = e >> 11;          // /2048
            const int r    = e & 2047;
            const int ci   = r >> 6;
            const int co   = r & 63;
            const int frag = (k << 2) | ((ci >> 4) << 1) | (co >> 5);
            const int ln   = (co & 31) | (((ci >> 3) & 1) << 5);
            const int j    = ci & 7;
            __bf16 hb = (__bf16)w4[m];
            wlds[frag * 512 + ln * 8 + j] = __builtin_bit_cast(unsigned short, hb);
        }
    }
    __syncthreads();

    const int rb = blockIdx.x * RPB + wv * RPWAVE;
    if (rb >= n) return;   // no barriers after this point

    // ---- preload all 27 neighbor indices for this lane's two rows ----
    const int row0 = rb + l31;            // tile 0
    const int row1 = rb + 32 + l31;       // tile 1
    const bool rv0 = row0 < n;
    const bool rv1 = row1 < n;
    const int* p0 = nbr + (size_t)min(row0, n - 1) * KV;
    const int* p1 = nbr + (size_t)min(row1, n - 1) * KV;

    i32x4u nA0[6], nA1[6];
    i32x2u nB0, nB1;
    int    nC0, nC1;
#pragma unroll
    for (int q = 0; q < 6; ++q) {
        nA0[q] = *(const i32x4u*)(p0 + 4 * q);
        nA1[q] = *(const i32x4u*)(p1 + 4 * q);
    }
    nB0 = *(const i32x2u*)(p0 + 24);  nC0 = p0[26];
    nB1 = *(const i32x2u*)(p1 + 24);  nC1 = p1[26];

    const float b0 = bias[l31];
    const float b1 = bias[l31 + 32];

    f32x16 acc[2][2] = {};   // [tile][co-half]

#pragma unroll
    for (int k = 0; k < KV; ++k) {
        // --- B fragments from LDS: 4 x ds_read_b128 ---
        const int fb = (k << 2) * 512 + lane * 8;
        const bf16x8 bB00 = *(const bf16x8*)&wlds[fb];          // c0,h0
        const bf16x8 bB01 = *(const bf16x8*)&wlds[fb + 512];    // c0,h1
        const bf16x8 bB10 = *(const bf16x8*)&wlds[fb + 1024];   // c1,h0
        const bf16x8 bB11 = *(const bf16x8*)&wlds[fb + 1536];   // c1,h1

        // --- A gather: per lane 16 f32 per tile (row = tile row, lane&31) ---
        const int  i0 = NIDX(nA0, nB0, nC0, k);
        const int  i1 = NIDX(nA1, nB1, nC1, k);
        const bool v0 = rv0 && (i0 != n);
        const bool v1 = rv1 && (i1 != n);
        // sentinel lanes clamp to row 0 (single shared cache line), zeroed below
        const float* f0 = feats + (size_t)(v0 ? i0 : 0) * CIN + 8 * e5;
        const float* f1 = feats + (size_t)(v1 ? i1 : 0) * CIN + 8 * e5;

        const f32x4a g0a = *(const f32x4a*)(f0);        // chunk0: ci = 8*e5 + 0..7
        const f32x4a g0b = *(const f32x4a*)(f0 + 4);
        const f32x4a g0c = *(const f32x4a*)(f0 + 16);   // chunk1: ci = 16 + 8*e5 + 0..7
        const f32x4a g0d = *(const f32x4a*)(f0 + 20);
        const f32x4a g1a = *(const f32x4a*)(f1);
        const f32x4a g1b = *(const f32x4a*)(f1 + 4);
        const f32x4a g1c = *(const f32x4a*)(f1 + 16);
        const f32x4a g1d = *(const f32x4a*)(f1 + 20);

        bf16x8 a00 = cvt8(g0a, g0b);   // tile0 chunk0
        bf16x8 a01 = cvt8(g0c, g0d);   // tile0 chunk1
        bf16x8 a10 = cvt8(g1a, g1b);   // tile1 chunk0
        bf16x8 a11 = cvt8(g1c, g1d);   // tile1 chunk1
        if (!v0) { a00 = bf16x8{}; a01 = bf16x8{}; }
        if (!v1) { a10 = bf16x8{}; a11 = bf16x8{}; }

        // --- 8 MFMAs: D[t][h] += A[t][c] * B[c][h] ---
        acc[0][0] = __builtin_amdgcn_mfma_f32_32x32x16_bf16(a00, bB00, acc[0][0], 0, 0, 0);
        acc[0][1] = __builtin_amdgcn_mfma_f32_32x32x16_bf16(a00, bB01, acc[0][1], 0, 0, 0);
        acc[0][0] = __builtin_amdgcn_mfma_f32_32x32x16_bf16(a01, bB10, acc[0][0], 0, 0, 0);
        acc[0][1] = __builtin_amdgcn_mfma_f32_32x32x16_bf16(a01, bB11, acc[0][1], 0, 0, 0);
        acc[1][0] = __builtin_amdgcn_mfma_f32_32x32x16_bf16(a10, bB00, acc[1][0], 0, 0, 0);
        acc[1][1] = __builtin_amdgcn_mfma_f32_32x32x16_bf16(a10, bB01, acc[1][1], 0, 0, 0);
        acc[1][0] = __builtin_amdgcn_mfma_f32_32x32x16_bf16(a11, bB10, acc[1][0], 0, 0, 0);
        acc[1][1] = __builtin_amdgcn_mfma_f32_32x32x16_bf16(a11, bB11, acc[1][1], 0, 0, 0);
    }

    // ---- epilogue: C/D layout col = lane&31, row = (reg&3)+8*(reg>>2)+4*e5 ----
#pragma unroll
    for (int h = 0; h < 2; ++h) {
        const float bb = h ? b1 : b0;
        const int   co = l31 + (h << 5);
#pragma unroll
        for (int r = 0; r < 16; ++r) {
            const int rr  = (r & 3) + ((r >> 2) << 3) + (e5 << 2);
            int row = rb + rr;
            if (row < n) out[(size_t)row * COUT + co] = acc[0][h][r] + bb;
            row += 32;
            if (row < n) out[(size_t)row * COUT + co] = acc[1][h][r] + bb;
        }
    }
}

extern "C" void kernel_launch(void* const* d_in, const int* in_sizes, int n_in,
                              void* d_out, int out_size, void* d_ws, size_t ws_size,
                              hipStream_t stream)
{
    const float* feats  = (const float*)d_in[0];   // (N, 32) f32
    const float* weight = (const float*)d_in[1];   // (27, 32, 64) f32
    const float* bias   = (const float*)d_in[2];   // (64,) f32
    const int*   nbr    = (const int*)  d_in[3];   // (N, 27) i32, sentinel = N

    float* out = (float*)d_out;                    // (N, 64) f32

    const int n    = in_sizes[0] / CIN;
    const int grid = (n + RPB - 1) / RPB;

    spconv_mfma_kernel<<<dim3(grid), dim3(512), 0, stream>>>(
        feats, weight, bias, nbr, out, n);
}

// Round 5
// 110.976 us; speedup vs baseline: 2.9612x; 1.3536x over previous
//
#include <hip/hip_runtime.h>

// Sparse submanifold 3D conv via dense bf16 MFMA (32x32x16). Round 5:
//  - 1024-thread blocks (16 waves, 1 tile of 32 rows each) -> 4 waves/SIMD
//    (R4 was 2/SIMD, LDS-capped at 1 block/CU; same 108 KiB LDS, more waves).
//  - XCD-contiguous block swizzle (T1, bijective m204): one XCD's resident
//    blocks cover consecutive rows -> gather working set ~2.6 MB fits 4 MB L2
//    (R4 gathers streamed 1.38 GB from L3 -> the 150 us was L3-bound).
//  - Prologue W->LDS: whole-fragment-per-wave conversion, linear
//    ds_write_b128 (R4: scattered ds_write_b16, 9.4M conflict cycles).
//  - Skip k entirely when all 32 rows of the wave are sentinel.

typedef short          bf16x8 __attribute__((ext_vector_type(8)));
typedef unsigned short u16x8  __attribute__((ext_vector_type(8)));
typedef float          f32x16 __attribute__((ext_vector_type(16)));
typedef float          f32x4a __attribute__((ext_vector_type(4)));
typedef int            i32x4u __attribute__((ext_vector_type(4), aligned(4)));
typedef int            i32x2u __attribute__((ext_vector_type(2), aligned(4)));

constexpr int CIN   = 32;
constexpr int COUT  = 64;
constexpr int KV    = 27;
constexpr int WAVES = 16;
constexpr int RPW   = 32;              // rows per wave (one 32x32 tile)
constexpr int RPB   = WAVES * RPW;     // 512 rows per block
constexpr int NFRAG = KV * 4;          // B fragments (k * {ci-chunk} * {co-half})
constexpr int SLOTS = NFRAG * 64;      // 6912 b128 LDS slots

__device__ inline bf16x8 cvt8(f32x4a lo, f32x4a hi) {
    bf16x8 r;
#pragma unroll
    for (int j = 0; j < 4; ++j) {
        r[j]     = __builtin_bit_cast(short, (__bf16)lo[j]);
        r[4 + j] = __builtin_bit_cast(short, (__bf16)hi[j]);
    }
    return r;
}

// static-index accessor into the preloaded nbr registers (folds after unroll)
#define NIDX(A, B, C, k) ((k) < 24 ? (A)[(k) >> 2][(k) & 3] \
                                   : ((k) < 26 ? (B)[(k) - 24] : (C)))

__global__ __launch_bounds__(1024, 4)
void spconv_mfma_kernel(const float* __restrict__ feats,
                        const float* __restrict__ weight,
                        const float* __restrict__ bias,
                        const int*   __restrict__ nbr,
                        float*       __restrict__ out,
                        int n, int nwg)
{
    // B fragments: frag = k*4 + cc*2 + h (cc = ci>>4 chunk, h = co>>5 half).
    // Lane holds 8 bf16 at halfword offset frag*512 + lane*8:
    //   col(co within half) = lane&31, kk = 8*(lane>>5) + j.
    __shared__ __align__(16) unsigned short wlds[NFRAG * 512];  // 108 KiB

    const int tid  = threadIdx.x;
    const int lane = tid & 63;
    const int wv   = tid >> 6;
    const int l31  = lane & 31;
    const int e5   = lane >> 5;

    // ---- prologue: W (f32 [k][ci][co]) -> LDS bf16, one fragment per
    //      wave-iteration, linear b128 writes (conflict-free) ----
#pragma unroll
    for (int i = 0; i < 7; ++i) {
        const int s = tid + 1024 * i;          // b128 slot = frag*64 + ln
        if (s < SLOTS) {
            const int frag = s >> 6;           // wave-uniform (frag = wv + 16*i)
            const int ln   = s & 63;
            const int k    = frag >> 2;
            const int cc   = (frag >> 1) & 1;
            const int h    = frag & 1;
            const int co   = (ln & 31) + (h << 5);
            const int cib  = (cc << 4) + ((ln >> 5) << 3);
            const float* src = weight + k * 2048 + cib * 64 + co;
            u16x8 t;
#pragma unroll
            for (int j = 0; j < 8; ++j)
                t[j] = __builtin_bit_cast(unsigned short, (__bf16)src[j * 64]);
            *(u16x8*)&wlds[s * 8] = t;         // ds_write_b128, stride 16B
        }
    }
    __syncthreads();

    // ---- XCD-contiguous block swizzle (bijective for any nwg) ----
    const int q    = nwg >> 3, r = nwg & 7;
    const int xcd  = blockIdx.x & 7, bidx = blockIdx.x >> 3;
    const int wg   = (xcd < r ? xcd * (q + 1) : r * (q + 1) + (xcd - r) * q) + bidx;

    const int rb = wg * RPB + wv * RPW;
    if (rb >= n) return;                       // wave-uniform, after the barrier

    // ---- preload all 27 neighbor indices for this lane's row ----
    const int  row = rb + l31;                 // lanes r and r+32 share a row
    const bool rv  = row < n;
    const int* p   = nbr + (size_t)min(row, n - 1) * KV;
    i32x4u nA[6]; i32x2u nB; int nC;
#pragma unroll
    for (int qq = 0; qq < 6; ++qq) nA[qq] = *(const i32x4u*)(p + 4 * qq);
    nB = *(const i32x2u*)(p + 24);
    nC = p[26];

    f32x16 acc0 = {}, acc1 = {};               // co-halves 0 / 1

#pragma unroll
    for (int k = 0; k < KV; ++k) {
        const int  ii = NIDX(nA, nB, nC, k);
        const bool v  = rv && (ii != n);
        if (__ballot(v) == 0ull) continue;     // whole tile empty at this k

        // A gather: lane reads 16 f32 of row `ii`: ci = {0,16} + 8*e5 + 0..7
        const float* f = feats + (size_t)(v ? ii : 0) * CIN + 8 * e5;
        const f32x4a g0 = *(const f32x4a*)(f);
        const f32x4a g1 = *(const f32x4a*)(f + 4);
        const f32x4a g2 = *(const f32x4a*)(f + 16);
        const f32x4a g3 = *(const f32x4a*)(f + 20);
        bf16x8 a0 = cvt8(g0, g1);              // ci-chunk 0
        bf16x8 a1 = cvt8(g2, g3);              // ci-chunk 1
        if (!v) { a0 = bf16x8{}; a1 = bf16x8{}; }

        // B fragments: 4 x ds_read_b128
        const int fb = (k << 2) * 512 + lane * 8;
        const bf16x8 b00 = *(const bf16x8*)&wlds[fb];
        const bf16x8 b01 = *(const bf16x8*)&wlds[fb + 512];
        const bf16x8 b10 = *(const bf16x8*)&wlds[fb + 1024];
        const bf16x8 b11 = *(const bf16x8*)&wlds[fb + 1536];

        acc0 = __builtin_amdgcn_mfma_f32_32x32x16_bf16(a0, b00, acc0, 0, 0, 0);
        acc1 = __builtin_amdgcn_mfma_f32_32x32x16_bf16(a0, b01, acc1, 0, 0, 0);
        acc0 = __builtin_amdgcn_mfma_f32_32x32x16_bf16(a1, b10, acc0, 0, 0, 0);
        acc1 = __builtin_amdgcn_mfma_f32_32x32x16_bf16(a1, b11, acc1, 0, 0, 0);
    }

    // ---- epilogue: C/D layout col=lane&31, row=(t&3)+8*(t>>2)+4*e5 ----
    const float bb0 = bias[l31];
    const float bb1 = bias[l31 + 32];
#pragma unroll
    for (int t = 0; t < 16; ++t) {
        const int rr   = (t & 3) + ((t >> 2) << 3) + (e5 << 2);
        const int orow = rb + rr;
        if (orow < n) {
            out[(size_t)orow * COUT + l31]      = acc0[t] + bb0;
            out[(size_t)orow * COUT + l31 + 32] = acc1[t] + bb1;
        }
    }
}

extern "C" void kernel_launch(void* const* d_in, const int* in_sizes, int n_in,
                              void* d_out, int out_size, void* d_ws, size_t ws_size,
                              hipStream_t stream)
{
    const float* feats  = (const float*)d_in[0];   // (N, 32) f32
    const float* weight = (const float*)d_in[1];   // (27, 32, 64) f32
    const float* bias   = (const float*)d_in[2];   // (64,) f32
    const int*   nbr    = (const int*)  d_in[3];   // (N, 27) i32, sentinel = N

    float* out = (float*)d_out;                    // (N, 64) f32

    const int n   = in_sizes[0] / CIN;
    const int nwg = (n + RPB - 1) / RPB;

    spconv_mfma_kernel<<<dim3(nwg), dim3(1024), 0, stream>>>(
        feats, weight, bias, nbr, out, n, nwg);
}

// Round 6
// 110.625 us; speedup vs baseline: 2.9705x; 1.0032x over previous
//
#include <hip/hip_runtime.h>

// Sparse submanifold 3D conv via dense bf16 MFMA (32x32x16). Round 6:
//  - DELETE the per-k ballot/continue (it fired ~4%: P(all 32 rows sentinel)
//    is tiny) -> fully branch-free unrolled k-loop so the compiler can
//    software-pipeline gather loads across k-iterations (R5: VGPR=52, zero
//    pipelining, every k a serial load->cvt->MFMA chain = latency-bound).
//  - __launch_bounds__(1024,4): VGPR cap 128. Occupancy is LDS-capped at
//    1 block/CU (16 waves) anyway, so regs 52->128 are free latency-hiding.
//  - Everything else from R5 kept: XCD-contiguous swizzle, conflict-free
//    fragment-ordered W->LDS prologue, register-preloaded nbr indices.

typedef short          bf16x8 __attribute__((ext_vector_type(8)));
typedef unsigned short u16x8  __attribute__((ext_vector_type(8)));
typedef float          f32x16 __attribute__((ext_vector_type(16)));
typedef float          f32x4a __attribute__((ext_vector_type(4)));
typedef int            i32x4u __attribute__((ext_vector_type(4), aligned(4)));
typedef int            i32x2u __attribute__((ext_vector_type(2), aligned(4)));

constexpr int CIN   = 32;
constexpr int COUT  = 64;
constexpr int KV    = 27;
constexpr int WAVES = 16;
constexpr int RPW   = 32;              // rows per wave (one 32x32 tile)
constexpr int RPB   = WAVES * RPW;     // 512 rows per block
constexpr int NFRAG = KV * 4;          // B fragments (k * {ci-chunk} * {co-half})
constexpr int SLOTS = NFRAG * 64;      // 6912 b128 LDS slots

__device__ inline bf16x8 cvt8(f32x4a lo, f32x4a hi) {
    bf16x8 r;
#pragma unroll
    for (int j = 0; j < 4; ++j) {
        r[j]     = __builtin_bit_cast(short, (__bf16)lo[j]);
        r[4 + j] = __builtin_bit_cast(short, (__bf16)hi[j]);
    }
    return r;
}

// static-index accessor into the preloaded nbr registers (folds after unroll)
#define NIDX(A, B, C, k) ((k) < 24 ? (A)[(k) >> 2][(k) & 3] \
                                   : ((k) < 26 ? (B)[(k) - 24] : (C)))

__global__ __launch_bounds__(1024, 4)
void spconv_mfma_kernel(const float* __restrict__ feats,
                        const float* __restrict__ weight,
                        const float* __restrict__ bias,
                        const int*   __restrict__ nbr,
                        float*       __restrict__ out,
                        int n, int nwg)
{
    // B fragments: frag = k*4 + cc*2 + h (cc = ci>>4 chunk, h = co>>5 half).
    // Lane holds 8 bf16 at halfword offset frag*512 + lane*8:
    //   col(co within half) = lane&31, kk = 8*(lane>>5) + j.
    __shared__ __align__(16) unsigned short wlds[NFRAG * 512];  // 108 KiB

    const int tid  = threadIdx.x;
    const int lane = tid & 63;
    const int wv   = tid >> 6;
    const int l31  = lane & 31;
    const int e5   = lane >> 5;

    // ---- prologue: W (f32 [k][ci][co]) -> LDS bf16, one fragment per
    //      wave-iteration, linear b128 writes (conflict-free) ----
#pragma unroll
    for (int i = 0; i < 7; ++i) {
        const int s = tid + 1024 * i;          // b128 slot = frag*64 + ln
        if (s < SLOTS) {
            const int frag = s >> 6;           // wave-uniform (frag = wv + 16*i)
            const int ln   = s & 63;
            const int k    = frag >> 2;
            const int cc   = (frag >> 1) & 1;
            const int h    = frag & 1;
            const int co   = (ln & 31) + (h << 5);
            const int cib  = (cc << 4) + ((ln >> 5) << 3);
            const float* src = weight + k * 2048 + cib * 64 + co;
            u16x8 t;
#pragma unroll
            for (int j = 0; j < 8; ++j)
                t[j] = __builtin_bit_cast(unsigned short, (__bf16)src[j * 64]);
            *(u16x8*)&wlds[s * 8] = t;         // ds_write_b128, stride 16B
        }
    }
    __syncthreads();

    // ---- XCD-contiguous block swizzle (bijective for any nwg) ----
    const int q    = nwg >> 3, r = nwg & 7;
    const int xcd  = blockIdx.x & 7, bidx = blockIdx.x >> 3;
    const int wg   = (xcd < r ? xcd * (q + 1) : r * (q + 1) + (xcd - r) * q) + bidx;

    const int rb = wg * RPB + wv * RPW;
    if (rb >= n) return;                       // wave-uniform, after the barrier

    // ---- preload all 27 neighbor indices for this lane's row ----
    const int  row = rb + l31;                 // lanes r and r+32 share a row
    const bool rv  = row < n;
    const int* p   = nbr + (size_t)min(row, n - 1) * KV;
    i32x4u nA[6]; i32x2u nB; int nC;
#pragma unroll
    for (int qq = 0; qq < 6; ++qq) nA[qq] = *(const i32x4u*)(p + 4 * qq);
    nB = *(const i32x2u*)(p + 24);
    nC = p[26];

    f32x16 acc0 = {}, acc1 = {};               // co-halves 0 / 1

    // ---- branch-free fully-unrolled k-loop: loads pipeline across k ----
#pragma unroll
    for (int k = 0; k < KV; ++k) {
        const int  ii = NIDX(nA, nB, nC, k);
        const bool v  = rv && (ii != n);

        // A gather: lane reads 16 f32 of row ii: ci = {0,16} + 8*e5 + 0..7
        // (sentinel lanes read the shared row 0 line, zeroed after cvt)
        const float* f = feats + (size_t)(v ? ii : 0) * CIN + 8 * e5;
        const f32x4a g0 = *(const f32x4a*)(f);
        const f32x4a g1 = *(const f32x4a*)(f + 4);
        const f32x4a g2 = *(const f32x4a*)(f + 16);
        const f32x4a g3 = *(const f32x4a*)(f + 20);
        bf16x8 a0 = cvt8(g0, g1);              // ci-chunk 0
        bf16x8 a1 = cvt8(g2, g3);              // ci-chunk 1
        if (!v) { a0 = bf16x8{}; a1 = bf16x8{}; }

        // B fragments: 4 x ds_read_b128
        const int fb = (k << 2) * 512 + lane * 8;
        const bf16x8 b00 = *(const bf16x8*)&wlds[fb];
        const bf16x8 b01 = *(const bf16x8*)&wlds[fb + 512];
        const bf16x8 b10 = *(const bf16x8*)&wlds[fb + 1024];
        const bf16x8 b11 = *(const bf16x8*)&wlds[fb + 1536];

        acc0 = __builtin_amdgcn_mfma_f32_32x32x16_bf16(a0, b00, acc0, 0, 0, 0);
        acc1 = __builtin_amdgcn_mfma_f32_32x32x16_bf16(a0, b01, acc1, 0, 0, 0);
        acc0 = __builtin_amdgcn_mfma_f32_32x32x16_bf16(a1, b10, acc0, 0, 0, 0);
        acc1 = __builtin_amdgcn_mfma_f32_32x32x16_bf16(a1, b11, acc1, 0, 0, 0);
    }

    // ---- epilogue: C/D layout col=lane&31, row=(t&3)+8*(t>>2)+4*e5 ----
    const float bb0 = bias[l31];
    const float bb1 = bias[l31 + 32];
#pragma unroll
    for (int t = 0; t < 16; ++t) {
        const int rr   = (t & 3) + ((t >> 2) << 3) + (e5 << 2);
        const int orow = rb + rr;
        if (orow < n) {
            out[(size_t)orow * COUT + l31]      = acc0[t] + bb0;
            out[(size_t)orow * COUT + l31 + 32] = acc1[t] + bb1;
        }
    }
}

extern "C" void kernel_launch(void* const* d_in, const int* in_sizes, int n_in,
                              void* d_out, int out_size, void* d_ws, size_t ws_size,
                              hipStream_t stream)
{
    const float* feats  = (const float*)d_in[0];   // (N, 32) f32
    const float* weight = (const float*)d_in[1];   // (27, 32, 64) f32
    const float* bias   = (const float*)d_in[2];   // (64,) f32
    const int*   nbr    = (const int*)  d_in[3];   // (N, 27) i32, sentinel = N

    float* out = (float*)d_out;                    // (N, 64) f32

    const int n   = in_sizes[0] / CIN;
    const int nwg = (n + RPB - 1) / RPB;

    spconv_mfma_kernel<<<dim3(nwg), dim3(1024), 0, stream>>>(
        feats, weight, bias, nbr, out, n, nwg);
}

// Round 7
// 91.796 us; speedup vs baseline: 3.5799x; 1.2051x over previous
//
#include <hip/hip_runtime.h>

// Sparse submanifold 3D conv via dense bf16 MFMA (32x32x16). Round 7:
//  - EXEC-MASKED GATHERS: the 4 feature loads + f32->bf16 cvt sit under a
//    per-lane `if (valid)`. R6 showed the limiter is not dependency latency
//    (removing branches changed nothing) but shared VMEM address/L1-tag
//    throughput: every gather instr processed 64 lane addresses, ~90% of
//    them sentinel lanes clamped to row 0. Masking them off cuts TA/L1
//    line-lookups ~10x (64 lanes -> ~6 valid lanes per instr).
//  - Everything else from R5/R6 kept: XCD-contiguous swizzle, conflict-free
//    fragment-ordered W->LDS prologue (108 KiB), register-preloaded nbr,
//    fully unrolled k-loop, static acc indexing.

typedef short          bf16x8 __attribute__((ext_vector_type(8)));
typedef unsigned short u16x8  __attribute__((ext_vector_type(8)));
typedef float          f32x16 __attribute__((ext_vector_type(16)));
typedef float          f32x4a __attribute__((ext_vector_type(4)));
typedef int            i32x4u __attribute__((ext_vector_type(4), aligned(4)));
typedef int            i32x2u __attribute__((ext_vector_type(2), aligned(4)));

constexpr int CIN   = 32;
constexpr int COUT  = 64;
constexpr int KV    = 27;
constexpr int WAVES = 16;
constexpr int RPW   = 32;              // rows per wave (one 32x32 tile)
constexpr int RPB   = WAVES * RPW;     // 512 rows per block
constexpr int NFRAG = KV * 4;          // B fragments (k * {ci-chunk} * {co-half})
constexpr int SLOTS = NFRAG * 64;      // 6912 b128 LDS slots

__device__ inline bf16x8 cvt8(f32x4a lo, f32x4a hi) {
    bf16x8 r;
#pragma unroll
    for (int j = 0; j < 4; ++j) {
        r[j]     = __builtin_bit_cast(short, (__bf16)lo[j]);
        r[4 + j] = __builtin_bit_cast(short, (__bf16)hi[j]);
    }
    return r;
}

// static-index accessor into the preloaded nbr registers (folds after unroll)
#define NIDX(A, B, C, k) ((k) < 24 ? (A)[(k) >> 2][(k) & 3] \
                                   : ((k) < 26 ? (B)[(k) - 24] : (C)))

__global__ __launch_bounds__(1024, 4)
void spconv_mfma_kernel(const float* __restrict__ feats,
                        const float* __restrict__ weight,
                        const float* __restrict__ bias,
                        const int*   __restrict__ nbr,
                        float*       __restrict__ out,
                        int n, int nwg)
{
    // B fragments: frag = k*4 + cc*2 + h (cc = ci>>4 chunk, h = co>>5 half).
    // Lane holds 8 bf16 at halfword offset frag*512 + lane*8:
    //   col(co within half) = lane&31, kk = 8*(lane>>5) + j.
    __shared__ __align__(16) unsigned short wlds[NFRAG * 512];  // 108 KiB

    const int tid  = threadIdx.x;
    const int lane = tid & 63;
    const int wv   = tid >> 6;
    const int l31  = lane & 31;
    const int e5   = lane >> 5;

    // ---- prologue: W (f32 [k][ci][co]) -> LDS bf16, one fragment per
    //      wave-iteration, linear b128 writes (conflict-free) ----
#pragma unroll
    for (int i = 0; i < 7; ++i) {
        const int s = tid + 1024 * i;          // b128 slot = frag*64 + ln
        if (s < SLOTS) {
            const int frag = s >> 6;           // wave-uniform (frag = wv + 16*i)
            const int ln   = s & 63;
            const int k    = frag >> 2;
            const int cc   = (frag >> 1) & 1;
            const int h    = frag & 1;
            const int co   = (ln & 31) + (h << 5);
            const int cib  = (cc << 4) + ((ln >> 5) << 3);
            const float* src = weight + k * 2048 + cib * 64 + co;
            u16x8 t;
#pragma unroll
            for (int j = 0; j < 8; ++j)
                t[j] = __builtin_bit_cast(unsigned short, (__bf16)src[j * 64]);
            *(u16x8*)&wlds[s * 8] = t;         // ds_write_b128, stride 16B
        }
    }
    __syncthreads();

    // ---- XCD-contiguous block swizzle (bijective for any nwg) ----
    const int q    = nwg >> 3, r = nwg & 7;
    const int xcd  = blockIdx.x & 7, bidx = blockIdx.x >> 3;
    const int wg   = (xcd < r ? xcd * (q + 1) : r * (q + 1) + (xcd - r) * q) + bidx;

    const int rb = wg * RPB + wv * RPW;
    if (rb >= n) return;                       // wave-uniform, after the barrier

    // ---- preload all 27 neighbor indices for this lane's row ----
    const int  row = rb + l31;                 // lanes r and r+32 share a row
    const bool rv  = row < n;
    const int* p   = nbr + (size_t)min(row, n - 1) * KV;
    i32x4u nA[6]; i32x2u nB; int nC;
#pragma unroll
    for (int qq = 0; qq < 6; ++qq) nA[qq] = *(const i32x4u*)(p + 4 * qq);
    nB = *(const i32x2u*)(p + 24);
    nC = p[26];

    f32x16 acc0 = {}, acc1 = {};               // co-halves 0 / 1

    // ---- fully-unrolled k-loop, exec-masked gathers ----
#pragma unroll
    for (int k = 0; k < KV; ++k) {
        const int  ii = NIDX(nA, nB, nC, k);
        const bool v  = rv && (ii != n);

        bf16x8 a0 = {}, a1 = {};
        if (v) {
            // lane reads 16 f32 of row ii: ci = {0,16} + 8*e5 + 0..7
            const float* f = feats + (size_t)ii * CIN + 8 * e5;
            const f32x4a g0 = *(const f32x4a*)(f);
            const f32x4a g1 = *(const f32x4a*)(f + 4);
            const f32x4a g2 = *(const f32x4a*)(f + 16);
            const f32x4a g3 = *(const f32x4a*)(f + 20);
            a0 = cvt8(g0, g1);                 // ci-chunk 0
            a1 = cvt8(g2, g3);                 // ci-chunk 1
        }

        // B fragments: 4 x ds_read_b128 (all lanes)
        const int fb = (k << 2) * 512 + lane * 8;
        const bf16x8 b00 = *(const bf16x8*)&wlds[fb];
        const bf16x8 b01 = *(const bf16x8*)&wlds[fb + 512];
        const bf16x8 b10 = *(const bf16x8*)&wlds[fb + 1024];
        const bf16x8 b11 = *(const bf16x8*)&wlds[fb + 1536];

        acc0 = __builtin_amdgcn_mfma_f32_32x32x16_bf16(a0, b00, acc0, 0, 0, 0);
        acc1 = __builtin_amdgcn_mfma_f32_32x32x16_bf16(a0, b01, acc1, 0, 0, 0);
        acc0 = __builtin_amdgcn_mfma_f32_32x32x16_bf16(a1, b10, acc0, 0, 0, 0);
        acc1 = __builtin_amdgcn_mfma_f32_32x32x16_bf16(a1, b11, acc1, 0, 0, 0);
    }

    // ---- epilogue: C/D layout col=lane&31, row=(t&3)+8*(t>>2)+4*e5 ----
    const float bb0 = bias[l31];
    const float bb1 = bias[l31 + 32];
#pragma unroll
    for (int t = 0; t < 16; ++t) {
        const int rr   = (t & 3) + ((t >> 2) << 3) + (e5 << 2);
        const int orow = rb + rr;
        if (orow < n) {
            out[(size_t)orow * COUT + l31]      = acc0[t] + bb0;
            out[(size_t)orow * COUT + l31 + 32] = acc1[t] + bb1;
        }
    }
}

extern "C" void kernel_launch(void* const* d_in, const int* in_sizes, int n_in,
                              void* d_out, int out_size, void* d_ws, size_t ws_size,
                              hipStream_t stream)
{
    const float* feats  = (const float*)d_in[0];   // (N, 32) f32
    const float* weight = (const float*)d_in[1];   // (27, 32, 64) f32
    const float* bias   = (const float*)d_in[2];   // (64,) f32
    const int*   nbr    = (const int*)  d_in[3];   // (N, 27) i32, sentinel = N

    float* out = (float*)d_out;                    // (N, 64) f32

    const int n   = in_sizes[0] / CIN;
    const int nwg = (n + RPB - 1) / RPB;

    spconv_mfma_kernel<<<dim3(nwg), dim3(1024), 0, stream>>>(
        feats, weight, bias, nbr, out, n, nwg);
}